// Round 9
// baseline (315.206 us; speedup 1.0000x reference)
//
#include <hip/hip_runtime.h>
#include <hip/hip_bf16.h>
#include <math.h>

// Problem constants
#define BN    8        // b*n = 4*2
#define H     480
#define W     640
#define CH    128
#define OH    120      // conv out h (stride 4, pad 3, k 7)
#define OW    160      // conv out w
#define P     192
#define PS    7
#define GH    16
#define GW    16
#define PH    30       // cell height  (480/16)
#define PW    40       // cell width   (640/16)

#define CONV_BLOCKS   2400   // 300 pixel-blocks x 8 channel groups
#define HARRIS_BLOCKS 2048   // BN * 256 cells

// ---------------------------------------------------------------------------
// Kernel 1 (MERGED): conv encoder + Harris, block-role partitioned.
// conv and harris are data-independent (conv: frame->fmap; harris:
// frame->cval/cidx) but were serialized back-to-back. Streams/events are
// forbidden under graph capture, so concurrency comes from ONE grid with
// interleaved block roles: evens of [0,4096) = conv, odds = harris, tail
// [4096,4448) = conv. Harris is VALU/LDS-heavy with low VMEM and fills
// conv's ~55% stall slots. Every block reserves harris's 29.2KB LDS ->
// 5 blocks/CU cap, above conv's observed ~2.3 resident blocks/CU.
// Conv body = EXACT R5 best (1x2 px pair x 16ch, direct loads, ~69us);
// harris body untouched -> bit-identical numerics for both.
// Conv history (keep!): LDS staging REGRESSED twice (113/84us); 2x2 px hit
// VGPR cliff (98us); forced launch_bounds SPILLED (483us); channel/pixel
// amortization all ~neutral -> ~70us is this structure's floor.
// !!! conv channel loop MUST stay one-channel-at-a-time with a single
// wave-uniform weight pointer. !!!
// !!! harris box sums are ACCUMULATION-ORDER-SENSITIVE: exact row-major
// (ky,kx) add chain per pixel; reassociation flips argmax ties. !!!
// ---------------------------------------------------------------------------
__global__ __launch_bounds__(256) void conv_harris(
    const float* __restrict__ f,
    const float* __restrict__ wf, const float* __restrict__ bf,
    float* __restrict__ fmap,
    float* __restrict__ cval, int* __restrict__ cidx)
{
    // harris LDS (reserved by all blocks; conv path leaves it unused)
    __shared__ float sf[37][48];
    __shared__ float dxx[36][48], dyy[36][48], dxy[36][48];
    __shared__ float sv[256];
    __shared__ int   si[256];

    int bid = blockIdx.x;
    int tid = threadIdx.x;
    bool is_conv;
    int widx;
    if (bid < 2 * HARRIS_BLOCKS) {       // [0,4096): interleave roles
        is_conv = (bid & 1) == 0;
        widx = bid >> 1;
    } else {                              // [4096,4448): conv tail
        is_conv = true;
        widx = HARRIS_BLOCKS + (bid - 2 * HARRIS_BLOCKS);
    }

    if (is_conv) {
        // ---- conv role: widx in [0, 2400) = pixel-block 0..299 x cgroup 0..7
        int pb = widx % 300;
        int cg = widx / 300;
        int pp = pb * 256 + tid;                 // pixel-pair index
        if (pp >= BN * OH * (OW / 2)) return;
        int c0 = cg * 16;
        int ox = 2 * (pp % (OW / 2));            // pixels (ox, ox+1)
        int t  = pp / (OW / 2);
        int oy = t % OH;
        int b  = t / OH;

        const float* fb = f + (size_t)b * H * W;
        int iy0 = 4 * oy - 3;
        int ix0 = 4 * ox - 3;
        // max ix = 4*158-3+10 = 639, max iy = 4*119-3+6 = 479: right/bottom
        // never out of range; only left/top need zero-fill.

        float in[77];                            // 7 rows x 11 cols
        if (oy > 0 && ox > 0) {
            #pragma unroll
            for (int ky = 0; ky < 7; ky++) {
                const float* row = fb + (iy0 + ky) * W + ix0;
                #pragma unroll
                for (int kx = 0; kx < 11; kx++) in[ky * 11 + kx] = row[kx];
            }
        } else {
            #pragma unroll
            for (int ky = 0; ky < 7; ky++) {
                int iy = iy0 + ky;
                #pragma unroll
                for (int kx = 0; kx < 11; kx++) {
                    int ix = ix0 + kx;
                    in[ky * 11 + kx] = (iy >= 0 && ix >= 0) ? fb[iy * W + ix] : 0.0f;
                }
            }
        }

        const size_t plane = (size_t)(OH * OW);
        size_t obase = (size_t)b * CH * plane + (size_t)oy * OW + ox;
        #pragma unroll 1
        for (int c = c0; c < c0 + 16; c++) {
            const float* wfc = wf + c * 49;
            float bias = bf[c];
            float a0 = bias, a1 = bias;
            #pragma unroll
            for (int ky = 0; ky < 7; ky++) {
                #pragma unroll
                for (int kx = 0; kx < 7; kx++) {
                    float wv = wfc[ky * 7 + kx];
                    a0 = fmaf(wv, in[ky * 11 + kx],     a0);
                    a1 = fmaf(wv, in[ky * 11 + kx + 4], a1);
                }
            }
            float2 r; r.x = fmaxf(a0, 0.0f); r.y = fmaxf(a1, 0.0f);
            *reinterpret_cast<float2*>(fmap + obase + (size_t)c * plane) = r;
        }
        return;
    }

    // ---- harris role: widx = cell in [0, 2048) ----
    int cell = widx;                  // b*256 + gh*16 + gw
    int b  = cell >> 8;
    int ci = cell & 255;
    int gh = ci >> 4, gw = ci & 15;
    int cy0 = gh * PH, cx0 = gw * PW;
    const float* fb = f + (size_t)b * H * W;

    // load f rows [cy0-3, cy0+33] (37), cols [cx0-3, cx0+43] (47), clamped
    for (int i = tid; i < 37 * 47; i += 256) {
        int r = i / 47, c = i % 47;
        int y = min(max(cy0 - 3 + r, 0), H - 1);
        int x = min(max(cx0 - 3 + c, 0), W - 1);
        sf[r][c] = fb[(size_t)y * W + x];
    }
    __syncthreads();

    // derivative products at rows [cy0-3, cy0+32] (36), cols [cx0-3, cx0+42] (46)
    for (int i = tid; i < 36 * 46; i += 256) {
        int r = i / 46, c = i % 46;
        int y = cy0 - 3 + r;
        int x = cx0 - 3 + c;
        float vxx = 0.0f, vyy = 0.0f, vxy = 0.0f;
        if (y >= 0 && y < H && x >= 0 && x < W) {
            int xa = (x == W - 1) ? (x - 2) : x;    // dx[639] = dx[637]
            int ya = (y == H - 1) ? (y - 2) : y;    // dy[479] = dy[477]
            int lx = xa - (cx0 - 3);
            int ly = ya - (cy0 - 3);
            float dxv = sf[r][lx + 1] - sf[r][lx];
            float dyv = sf[ly + 1][c] - sf[ly][c];
            vxx = dxv * dxv;
            vyy = dyv * dyv;
            vxy = dxv * dyv;
        }
        dxx[r][c] = vxx; dyy[r][c] = vyy; dxy[r][c] = vxy;
    }
    __syncthreads();

    // Register-blocked box sums: thread = (col, 6-pixel vertical group).
    float best = -INFINITY;
    int   bidx = 0x7fffffff;
    if (tid < 200) {
        int col = tid % 40;           // ix
        int grp = tid / 40;           // iy0 = grp*6, pixels iy0..iy0+5
        int iy0 = grp * 6;
        float axx[6] = {0,0,0,0,0,0};
        float ayy[6] = {0,0,0,0,0,0};
        float axy[6] = {0,0,0,0,0,0};
        #pragma unroll
        for (int r = 0; r < 12; r++) {
            float vxx[7], vyy[7], vxy[7];
            #pragma unroll
            for (int kx = 0; kx < 7; kx++) {
                vxx[kx] = dxx[iy0 + r][col + kx];
                vyy[kx] = dyy[iy0 + r][col + kx];
                vxy[kx] = dxy[iy0 + r][col + kx];
            }
            #pragma unroll
            for (int p = 0; p < 6; p++) {
                if (r - p >= 0 && r - p <= 6) {   // pixel p uses rows p..p+6
                    #pragma unroll
                    for (int kx = 0; kx < 7; kx++) {
                        axx[p] += vxx[kx];
                        ayy[p] += vyy[kx];
                        axy[p] += vxy[kx];
                    }
                }
            }
        }
        #pragma unroll
        for (int p = 0; p < 6; p++) {
            float Ixx = axx[p] / 49.0f;
            float Iyy = ayy[p] / 49.0f;
            float Ixy = axy[p] / 49.0f;
            float resp = (Ixx * Iyy - Ixy * Ixy) / (Ixx + Iyy + 1e-8f);
            int idx = (iy0 + p) * PW + col;
            if (resp > best) { best = resp; bidx = idx; }
        }
    }

    sv[tid] = best;
    si[tid] = bidx;
    __syncthreads();
    for (int s = 128; s > 0; s >>= 1) {
        if (tid < s) {
            float ov = sv[tid + s];
            int   oi = si[tid + s];
            if (ov > sv[tid] || (ov == sv[tid] && oi < si[tid])) {
                sv[tid] = ov; si[tid] = oi;
            }
        }
        __syncthreads();
    }
    if (tid == 0) { cval[cell] = sv[0]; cidx[cell] = si[0]; }
}

// ---------------------------------------------------------------------------
// Kernel 3: stable top-192 of 256 cell maxima per batch via O(256^2) ranking
// ---------------------------------------------------------------------------
__global__ __launch_bounds__(256) void topk_coords(
    const float* __restrict__ cval, const int* __restrict__ cidx,
    float* __restrict__ coords)
{
    int b = blockIdx.x;
    int j = threadIdx.x;
    __shared__ float v[256];
    v[j] = cval[b * 256 + j];
    __syncthreads();
    float vj = v[j];
    int rank = 0;
    for (int k = 0; k < 256; k++) {
        float vk = v[k];
        rank += (vk > vj) || (vk == vj && k < j);
    }
    if (rank < P) {
        int ii = cidx[b * 256 + j];
        int gh = j >> 4, gw = j & 15;
        int y = ii / PW + gh * PH;
        int x = ii % PW + gw * PW;
        coords[((size_t)b * P + rank) * 2 + 0] = (float)x;
        coords[((size_t)b * P + rank) * 2 + 1] = (float)y;
    }
}

// ---------------------------------------------------------------------------
// Kernel 4: patches. One block per (b,p) point. All 49 taps share one
// bilinear fraction; stage the 8x8x128 fmap window in LDS.
// patches_c: on-the-fly second conv at the 4 corner pixels.
// (R8's LDS weight-cache restructure was NEUTRAL -> reverted to the exact
// version from the best-measured 252.6us configuration.)
// ---------------------------------------------------------------------------
__global__ __launch_bounds__(256) void patches_kern(
    const float* __restrict__ coords,
    const float* __restrict__ fmap,
    const float* __restrict__ frame,
    const float* __restrict__ wc, const float* __restrict__ bc,
    float* __restrict__ pf, float* __restrict__ pc)
{
    __shared__ float sfm[CH][64];      // 8 rows x 8 cols per channel, 32 KB
    __shared__ float sf2[14][16];
    __shared__ float vq[CH][5];

    int bp = blockIdx.x;               // 0 .. BN*P
    int b = bp / P;
    float cx = coords[(size_t)bp * 2 + 0] * 0.25f;   // /DS, exact
    float cy = coords[(size_t)bp * 2 + 1] * 0.25f;
    int tid = threadIdx.x;

    int X0 = (int)floorf(cx), Y0 = (int)floorf(cy);
    float wx = cx - (float)X0, wy = cy - (float)Y0;
    float w00 = (1.0f - wx) * (1.0f - wy);
    float w10 = wx * (1.0f - wy);
    float w01 = (1.0f - wx) * wy;
    float w11 = wx * wy;

    // stage fmap window rows [Y0-3, Y0+4], cols [X0-3, X0+4], all channels
    const float* fm = fmap + (size_t)b * CH * (OH * OW);
    for (int i = tid; i < CH * 64; i += 256) {
        int ch = i >> 6;
        int off = i & 63;
        int r = off >> 3, c = off & 7;
        int gy = Y0 - 3 + r, gx = X0 - 3 + c;
        sfm[ch][off] = (gy >= 0 && gy < OH && gx >= 0 && gx < OW)
                     ? fm[(size_t)ch * (OH * OW) + gy * OW + gx] : 0.0f;
    }

    // stage 14x14 input patch for the on-the-fly conv (zero outside image)
    int ix0 = 4 * X0 - 3, iy0 = 4 * Y0 - 3;
    const float* frb = frame + (size_t)b * H * W;
    for (int i = tid; i < 14 * 14; i += 256) {
        int r = i / 14, c = i % 14;
        int y = iy0 + r, x = ix0 + c;
        sf2[r][c] = (y >= 0 && y < H && x >= 0 && x < W)
                  ? frb[(size_t)y * W + x] : 0.0f;
    }
    __syncthreads();

    // ---- patches_f: bilinear from LDS ----
    size_t pfbase = (size_t)bp * CH * 49;
    for (int idx = tid; idx < CH * 49; idx += 256) {
        int c = idx / 49;
        int k = idx - c * 49;
        int ky = k / 7, kx = k - ky * 7;
        int o = ky * 8 + kx;
        float acc = w00 * sfm[c][o]
                  + w10 * sfm[c][o + 1]
                  + w01 * sfm[c][o + 8]
                  + w11 * sfm[c][o + 9];
        pf[pfbase + idx] = acc;
    }

    // ---- on-the-fly second conv at the 4 corner pixels ----
    for (int idx = tid; idx < 512; idx += 256) {
        int q = idx & 3;            // (qx,qy) = (q&1, q>>1)
        int c = idx >> 2;
        int qx = q & 1, qy = q >> 1;
        const float* wcc = wc + c * 49;
        float acc = bc[c];
        #pragma unroll
        for (int ky = 0; ky < 7; ky++) {
            #pragma unroll
            for (int kx = 0; kx < 7; kx++)
                acc = fmaf(wcc[ky * 7 + kx], sf2[4 * qy + ky][4 * qx + kx], acc);
        }
        vq[c][q] = fmaxf(acc, 0.0f);
    }
    __syncthreads();

    // ---- patches_c: bilinear combine with boundary masks ----
    float m00 = (X0 >= 0 && X0 < OW && Y0 >= 0 && Y0 < OH) ? 1.0f : 0.0f;
    float m10 = (X0 + 1 >= 0 && X0 + 1 < OW && Y0 >= 0 && Y0 < OH) ? 1.0f : 0.0f;
    float m01 = (X0 >= 0 && X0 < OW && Y0 + 1 >= 0 && Y0 + 1 < OH) ? 1.0f : 0.0f;
    float m11 = (X0 + 1 >= 0 && X0 + 1 < OW && Y0 + 1 >= 0 && Y0 + 1 < OH) ? 1.0f : 0.0f;
    if (tid < CH) {
        float acc = w00 * m00 * vq[tid][0] + w10 * m10 * vq[tid][1]
                  + w01 * m01 * vq[tid][2] + w11 * m11 * vq[tid][3];
        pc[(size_t)bp * CH + tid] = acc;
    }
}

// ---------------------------------------------------------------------------
// Launch
// ---------------------------------------------------------------------------
extern "C" void kernel_launch(void* const* d_in, const int* in_sizes, int n_in,
                              void* d_out, int out_size, void* d_ws, size_t ws_size,
                              hipStream_t stream)
{
    const float* frame = (const float*)d_in[0];
    const float* w_f   = (const float*)d_in[1];
    const float* b_f   = (const float*)d_in[2];
    const float* w_c   = (const float*)d_in[3];
    const float* b_c   = (const float*)d_in[4];

    float* out = (float*)d_out;
    // output layout: coords | patches_f | patches_c | fmap
    const size_t coords_sz = (size_t)BN * P * 2;                 // 3072
    const size_t pf_sz     = (size_t)BN * P * CH * 49;           // 9,633,792
    const size_t pc_sz     = (size_t)BN * P * CH;                // 196,608
    float* coords = out;
    float* pf     = out + coords_sz;
    float* pc     = out + coords_sz + pf_sz;
    float* fmap   = out + coords_sz + pf_sz + pc_sz;

    // workspace: only cell argmax state (16 KB)
    float* cval = (float*)d_ws;                                  // 2048 f
    int*   cidx = (int*)(cval + BN * 256);                       // 2048 i

    // merged conv (2400 roles) + harris (2048 roles), interleaved
    conv_harris<<<CONV_BLOCKS + HARRIS_BLOCKS, 256, 0, stream>>>(
        frame, w_f, b_f, fmap, cval, cidx);

    topk_coords<<<BN, 256, 0, stream>>>(cval, cidx, coords);

    patches_kern<<<BN * P, 256, 0, stream>>>(
        coords, fmap, frame, w_c, b_c, pf, pc);
}

// Round 10
// 266.757 us; speedup vs baseline: 1.1816x; 1.1816x over previous
//
#include <hip/hip_runtime.h>
#include <hip/hip_bf16.h>
#include <math.h>

// Problem constants
#define BN    8        // b*n = 4*2
#define H     480
#define W     640
#define CH    128
#define OH    120      // conv out h (stride 4, pad 3, k 7)
#define OW    160      // conv out w
#define P     192
#define PS    7
#define GH    16
#define GW    16
#define PH    30       // cell height  (480/16)
#define PW    40       // cell width   (640/16)

// ---------------------------------------------------------------------------
// Kernel 1: conv encoder fmap. R5-best body (1x2 px pair x 16 ch, direct
// loads, total 252.6us) with ONE change: channel loop `#pragma unroll 2`
// (single wave-uniform weight pointer kept; compiler may overlap channel
// c+1's s_load burst with channel c's 98 FMAs).
// History (keep!):
//   - ~70us floor across: 1px x 8ch (74), 1px x 16ch (~70), 1x2px x 16ch
//     (~69, BEST). LDS staging REGRESSED twice (113/84us) even with perfect
//     coalescing — R7's channel loop had ZERO vector-mem deps yet stalled
//     70% -> stall is lgkmcnt on per-channel weight s_loads, serialized by
//     unroll 1 (hypothesis under test here).
//   - 2x2 px (180 VGPR): 98us occ cliff. Forced launch_bounds: 483us SPILL.
//   - R9 conv+harris block-role merge: 163.8us — union footprint (VGPR 136,
//     30KB LDS on every block) -> occ 10%. Merging needs footprint <= each
//     role's standalone; revert.
//   - "multi-pointer ILP" historical regression used SEPARATE weight
//     pointers; unroll-2 over one pointer is a different (untested) path.
// Per-channel FMA chain stays exact k-ascending row-major; channels are
// independent -> bit-identical numerics.
// ---------------------------------------------------------------------------
__global__ __launch_bounds__(256) void conv_enc(
    const float* __restrict__ f,
    const float* __restrict__ wf, const float* __restrict__ bf,
    float* __restrict__ fmap)
{
    int pp = blockIdx.x * blockDim.x + threadIdx.x;   // pixel-pair index
    if (pp >= BN * OH * (OW / 2)) return;
    int c0 = blockIdx.y * 16;            // channel group
    int ox = 2 * (pp % (OW / 2));        // pixels (ox, ox+1)
    int t  = pp / (OW / 2);
    int oy = t % OH;
    int b  = t / OH;

    const float* fb = f + (size_t)b * H * W;
    int iy0 = 4 * oy - 3;
    int ix0 = 4 * ox - 3;
    // second pixel's window starts at ix0+4, ends ix0+10.
    // max ix = 4*158-3+10 = 639, max iy = 4*119-3+6 = 479: right/bottom
    // never out of range; only left/top need zero-fill.

    float in[77];                        // 7 rows x 11 cols
    if (oy > 0 && ox > 0) {
        #pragma unroll
        for (int ky = 0; ky < 7; ky++) {
            const float* row = fb + (iy0 + ky) * W + ix0;
            #pragma unroll
            for (int kx = 0; kx < 11; kx++) in[ky * 11 + kx] = row[kx];
        }
    } else {
        #pragma unroll
        for (int ky = 0; ky < 7; ky++) {
            int iy = iy0 + ky;
            #pragma unroll
            for (int kx = 0; kx < 11; kx++) {
                int ix = ix0 + kx;
                in[ky * 11 + kx] = (iy >= 0 && ix >= 0) ? fb[iy * W + ix] : 0.0f;
            }
        }
    }

    const size_t plane = (size_t)(OH * OW);
    size_t obase = (size_t)b * CH * plane + (size_t)oy * OW + ox;
    #pragma unroll 2
    for (int c = c0; c < c0 + 16; c++) {
        const float* wfc = wf + c * 49;
        float bias = bf[c];
        float a0 = bias, a1 = bias;
        #pragma unroll
        for (int ky = 0; ky < 7; ky++) {
            #pragma unroll
            for (int kx = 0; kx < 7; kx++) {
                float wv = wfc[ky * 7 + kx];
                a0 = fmaf(wv, in[ky * 11 + kx],     a0);
                a1 = fmaf(wv, in[ky * 11 + kx + 4], a1);
            }
        }
        float2 r; r.x = fmaxf(a0, 0.0f); r.y = fmaxf(a1, 0.0f);
        // 8B-aligned: ox and OW even
        *reinterpret_cast<float2*>(fmap + obase + (size_t)c * plane) = r;
    }
}

// ---------------------------------------------------------------------------
// Kernel 2: fused Harris + per-cell argmax. One block per grid cell (30x40).
// !!! ACCUMULATION-ORDER-SENSITIVE: each pixel's 7x7 box sum MUST be the
// direct row-major (ky,kx) chain of individual adds. Separable / row-sum
// reassociation flips argmax ties (rounds 1 & 4: absmax 468). The register
// blocking below shares LDS READS only — every pixel still executes its own
// exact 49-add chain per array. !!!
// ---------------------------------------------------------------------------
__global__ __launch_bounds__(256) void harris_cell(
    const float* __restrict__ f, float* __restrict__ cval, int* __restrict__ cidx)
{
    __shared__ float sf[37][48];
    __shared__ float dxx[36][48], dyy[36][48], dxy[36][48];
    __shared__ float sv[256];
    __shared__ int   si[256];

    int cell = blockIdx.x;            // b*256 + gh*16 + gw
    int b  = cell >> 8;
    int ci = cell & 255;
    int gh = ci >> 4, gw = ci & 15;
    int cy0 = gh * PH, cx0 = gw * PW;
    const float* fb = f + (size_t)b * H * W;
    int tid = threadIdx.x;

    // load f rows [cy0-3, cy0+33] (37), cols [cx0-3, cx0+43] (47), clamped
    for (int i = tid; i < 37 * 47; i += 256) {
        int r = i / 47, c = i % 47;
        int y = min(max(cy0 - 3 + r, 0), H - 1);
        int x = min(max(cx0 - 3 + c, 0), W - 1);
        sf[r][c] = fb[(size_t)y * W + x];
    }
    __syncthreads();

    // derivative products at rows [cy0-3, cy0+32] (36), cols [cx0-3, cx0+42] (46)
    for (int i = tid; i < 36 * 46; i += 256) {
        int r = i / 46, c = i % 46;
        int y = cy0 - 3 + r;
        int x = cx0 - 3 + c;
        float vxx = 0.0f, vyy = 0.0f, vxy = 0.0f;
        if (y >= 0 && y < H && x >= 0 && x < W) {
            int xa = (x == W - 1) ? (x - 2) : x;    // dx[639] = dx[637]
            int ya = (y == H - 1) ? (y - 2) : y;    // dy[479] = dy[477]
            int lx = xa - (cx0 - 3);
            int ly = ya - (cy0 - 3);
            float dxv = sf[r][lx + 1] - sf[r][lx];
            float dyv = sf[ly + 1][c] - sf[ly][c];
            vxx = dxv * dxv;
            vyy = dyv * dyv;
            vxy = dxv * dyv;
        }
        dxx[r][c] = vxx; dyy[r][c] = vyy; dxy[r][c] = vxy;
    }
    __syncthreads();

    // Register-blocked box sums: thread = (col, 6-pixel vertical group).
    // Load each derivative row once (21 regs), add each value individually
    // to every covered pixel in exact (ky,kx) row-major order.
    float best = -INFINITY;
    int   bidx = 0x7fffffff;
    if (tid < 200) {
        int col = tid % 40;           // ix
        int grp = tid / 40;           // iy0 = grp*6, pixels iy0..iy0+5
        int iy0 = grp * 6;
        float axx[6] = {0,0,0,0,0,0};
        float ayy[6] = {0,0,0,0,0,0};
        float axy[6] = {0,0,0,0,0,0};
        #pragma unroll
        for (int r = 0; r < 12; r++) {
            float vxx[7], vyy[7], vxy[7];
            #pragma unroll
            for (int kx = 0; kx < 7; kx++) {
                vxx[kx] = dxx[iy0 + r][col + kx];
                vyy[kx] = dyy[iy0 + r][col + kx];
                vxy[kx] = dxy[iy0 + r][col + kx];
            }
            #pragma unroll
            for (int p = 0; p < 6; p++) {
                if (r - p >= 0 && r - p <= 6) {   // pixel p uses rows p..p+6
                    #pragma unroll
                    for (int kx = 0; kx < 7; kx++) {
                        axx[p] += vxx[kx];
                        ayy[p] += vyy[kx];
                        axy[p] += vxy[kx];
                    }
                }
            }
        }
        #pragma unroll
        for (int p = 0; p < 6; p++) {
            float Ixx = axx[p] / 49.0f;
            float Iyy = ayy[p] / 49.0f;
            float Ixy = axy[p] / 49.0f;
            float resp = (Ixx * Iyy - Ixy * Ixy) / (Ixx + Iyy + 1e-8f);
            int idx = (iy0 + p) * PW + col;
            if (resp > best) { best = resp; bidx = idx; }
        }
    }

    sv[tid] = best;
    si[tid] = bidx;
    __syncthreads();
    for (int s = 128; s > 0; s >>= 1) {
        if (tid < s) {
            float ov = sv[tid + s];
            int   oi = si[tid + s];
            if (ov > sv[tid] || (ov == sv[tid] && oi < si[tid])) {
                sv[tid] = ov; si[tid] = oi;
            }
        }
        __syncthreads();
    }
    if (tid == 0) { cval[cell] = sv[0]; cidx[cell] = si[0]; }
}

// ---------------------------------------------------------------------------
// Kernel 3: stable top-192 of 256 cell maxima per batch via O(256^2) ranking
// ---------------------------------------------------------------------------
__global__ __launch_bounds__(256) void topk_coords(
    const float* __restrict__ cval, const int* __restrict__ cidx,
    float* __restrict__ coords)
{
    int b = blockIdx.x;
    int j = threadIdx.x;
    __shared__ float v[256];
    v[j] = cval[b * 256 + j];
    __syncthreads();
    float vj = v[j];
    int rank = 0;
    for (int k = 0; k < 256; k++) {
        float vk = v[k];
        rank += (vk > vj) || (vk == vj && k < j);
    }
    if (rank < P) {
        int ii = cidx[b * 256 + j];
        int gh = j >> 4, gw = j & 15;
        int y = ii / PW + gh * PH;
        int x = ii % PW + gw * PW;
        coords[((size_t)b * P + rank) * 2 + 0] = (float)x;
        coords[((size_t)b * P + rank) * 2 + 1] = (float)y;
    }
}

// ---------------------------------------------------------------------------
// Kernel 4: patches. One block per (b,p) point. All 49 taps share one
// bilinear fraction; stage the 8x8x128 fmap window in LDS.
// patches_c: on-the-fly second conv at the 4 corner pixels.
// (R8's LDS weight-cache restructure was NEUTRAL -> exact best-config
// version kept.)
// ---------------------------------------------------------------------------
__global__ __launch_bounds__(256) void patches_kern(
    const float* __restrict__ coords,
    const float* __restrict__ fmap,
    const float* __restrict__ frame,
    const float* __restrict__ wc, const float* __restrict__ bc,
    float* __restrict__ pf, float* __restrict__ pc)
{
    __shared__ float sfm[CH][64];      // 8 rows x 8 cols per channel, 32 KB
    __shared__ float sf2[14][16];
    __shared__ float vq[CH][5];

    int bp = blockIdx.x;               // 0 .. BN*P
    int b = bp / P;
    float cx = coords[(size_t)bp * 2 + 0] * 0.25f;   // /DS, exact
    float cy = coords[(size_t)bp * 2 + 1] * 0.25f;
    int tid = threadIdx.x;

    int X0 = (int)floorf(cx), Y0 = (int)floorf(cy);
    float wx = cx - (float)X0, wy = cy - (float)Y0;
    float w00 = (1.0f - wx) * (1.0f - wy);
    float w10 = wx * (1.0f - wy);
    float w01 = (1.0f - wx) * wy;
    float w11 = wx * wy;

    // stage fmap window rows [Y0-3, Y0+4], cols [X0-3, X0+4], all channels
    const float* fm = fmap + (size_t)b * CH * (OH * OW);
    for (int i = tid; i < CH * 64; i += 256) {
        int ch = i >> 6;
        int off = i & 63;
        int r = off >> 3, c = off & 7;
        int gy = Y0 - 3 + r, gx = X0 - 3 + c;
        sfm[ch][off] = (gy >= 0 && gy < OH && gx >= 0 && gx < OW)
                     ? fm[(size_t)ch * (OH * OW) + gy * OW + gx] : 0.0f;
    }

    // stage 14x14 input patch for the on-the-fly conv (zero outside image)
    int ix0 = 4 * X0 - 3, iy0 = 4 * Y0 - 3;
    const float* frb = frame + (size_t)b * H * W;
    for (int i = tid; i < 14 * 14; i += 256) {
        int r = i / 14, c = i % 14;
        int y = iy0 + r, x = ix0 + c;
        sf2[r][c] = (y >= 0 && y < H && x >= 0 && x < W)
                  ? frb[(size_t)y * W + x] : 0.0f;
    }
    __syncthreads();

    // ---- patches_f: bilinear from LDS ----
    size_t pfbase = (size_t)bp * CH * 49;
    for (int idx = tid; idx < CH * 49; idx += 256) {
        int c = idx / 49;
        int k = idx - c * 49;
        int ky = k / 7, kx = k - ky * 7;
        int o = ky * 8 + kx;
        float acc = w00 * sfm[c][o]
                  + w10 * sfm[c][o + 1]
                  + w01 * sfm[c][o + 8]
                  + w11 * sfm[c][o + 9];
        pf[pfbase + idx] = acc;
    }

    // ---- on-the-fly second conv at the 4 corner pixels ----
    for (int idx = tid; idx < 512; idx += 256) {
        int q = idx & 3;            // (qx,qy) = (q&1, q>>1)
        int c = idx >> 2;
        int qx = q & 1, qy = q >> 1;
        const float* wcc = wc + c * 49;
        float acc = bc[c];
        #pragma unroll
        for (int ky = 0; ky < 7; ky++) {
            #pragma unroll
            for (int kx = 0; kx < 7; kx++)
                acc = fmaf(wcc[ky * 7 + kx], sf2[4 * qy + ky][4 * qx + kx], acc);
        }
        vq[c][q] = fmaxf(acc, 0.0f);
    }
    __syncthreads();

    // ---- patches_c: bilinear combine with boundary masks ----
    float m00 = (X0 >= 0 && X0 < OW && Y0 >= 0 && Y0 < OH) ? 1.0f : 0.0f;
    float m10 = (X0 + 1 >= 0 && X0 + 1 < OW && Y0 >= 0 && Y0 < OH) ? 1.0f : 0.0f;
    float m01 = (X0 >= 0 && X0 < OW && Y0 + 1 >= 0 && Y0 + 1 < OH) ? 1.0f : 0.0f;
    float m11 = (X0 + 1 >= 0 && X0 + 1 < OW && Y0 + 1 >= 0 && Y0 + 1 < OH) ? 1.0f : 0.0f;
    if (tid < CH) {
        float acc = w00 * m00 * vq[tid][0] + w10 * m10 * vq[tid][1]
                  + w01 * m01 * vq[tid][2] + w11 * m11 * vq[tid][3];
        pc[(size_t)bp * CH + tid] = acc;
    }
}

// ---------------------------------------------------------------------------
// Launch
// ---------------------------------------------------------------------------
extern "C" void kernel_launch(void* const* d_in, const int* in_sizes, int n_in,
                              void* d_out, int out_size, void* d_ws, size_t ws_size,
                              hipStream_t stream)
{
    const float* frame = (const float*)d_in[0];
    const float* w_f   = (const float*)d_in[1];
    const float* b_f   = (const float*)d_in[2];
    const float* w_c   = (const float*)d_in[3];
    const float* b_c   = (const float*)d_in[4];

    float* out = (float*)d_out;
    // output layout: coords | patches_f | patches_c | fmap
    const size_t coords_sz = (size_t)BN * P * 2;                 // 3072
    const size_t pf_sz     = (size_t)BN * P * CH * 49;           // 9,633,792
    const size_t pc_sz     = (size_t)BN * P * CH;                // 196,608
    float* coords = out;
    float* pf     = out + coords_sz;
    float* pc     = out + coords_sz + pf_sz;
    float* fmap   = out + coords_sz + pf_sz + pc_sz;

    // workspace: only cell argmax state (16 KB)
    float* cval = (float*)d_ws;                                  // 2048 f
    int*   cidx = (int*)(cval + BN * 256);                       // 2048 i

    // 76800 pixel-pairs / 256 = 300 blocks x 8 channel groups (16 ch/thread)
    dim3 cg((BN * OH * (OW / 2)) / 256, 8);
    conv_enc<<<cg, 256, 0, stream>>>(frame, w_f, b_f, fmap);

    harris_cell<<<BN * 256, 256, 0, stream>>>(frame, cval, cidx);

    topk_coords<<<BN, 256, 0, stream>>>(cval, cidx, coords);

    patches_kern<<<BN * P, 256, 0, stream>>>(
        coords, fmap, frame, w_c, b_c, pf, pc);
}

// Round 11
// 246.891 us; speedup vs baseline: 1.2767x; 1.0805x over previous
//
#include <hip/hip_runtime.h>
#include <hip/hip_bf16.h>
#include <math.h>

// Problem constants
#define BN    8        // b*n = 4*2
#define H     480
#define W     640
#define CH    128
#define OH    120      // conv out h (stride 4, pad 3, k 7)
#define OW    160      // conv out w
#define P     192
#define PS    7
#define GH    16
#define GW    16
#define PH    30       // cell height  (480/16)
#define PW    40       // cell width   (640/16)

typedef float v2f __attribute__((ext_vector_type(2)));

// ---------------------------------------------------------------------------
// Kernel 1: conv encoder fmap. EXACT R5-best body (1x2 px pair x 16 ch,
// direct loads, unroll 1 -> total 252.6us) + NONTEMPORAL fmap stores.
// Theory: every conv variant streams 76.8MB of output through L2, evicting
// the frame working set (1.2MB/XCD would otherwise be L2-resident), so the
// line-amplified window reads (16-32 lines/wave-load) fall through to L3 —
// the one mechanism common to ALL variants at the ~70us floor. nt stores
// keep identical bits but stop the pollution.
// History (keep!):
//   - ~70us floor: 1px x 8ch (74) / 1px x 16ch (~70) / 1x2px x 16ch (69,
//     BEST) / LDS-staged 8ch (113) / LDS-staged 32ch (84).
//   - 2x2 px (180 VGPR): 98us occ cliff. Forced launch_bounds: 483us SPILL.
//   - unroll 2 on channel loop: 80us — VGPR 124, occ 19%, FETCH 5x. REVERTED.
//   - R9 conv+harris block-role merge: 164us (union footprint -> occ 10%).
//   - Timed budget: ~144us poison-fill (harness, fixed) + conv + ~37us rest.
// !!! Channel loop MUST stay unroll 1, one-channel-at-a-time, single
// wave-uniform weight pointer. FMA chain exact k-ascending row-major ->
// bit-identical numerics. !!!
// ---------------------------------------------------------------------------
__global__ __launch_bounds__(256) void conv_enc(
    const float* __restrict__ f,
    const float* __restrict__ wf, const float* __restrict__ bf,
    float* __restrict__ fmap)
{
    int pp = blockIdx.x * blockDim.x + threadIdx.x;   // pixel-pair index
    if (pp >= BN * OH * (OW / 2)) return;
    int c0 = blockIdx.y * 16;            // channel group
    int ox = 2 * (pp % (OW / 2));        // pixels (ox, ox+1)
    int t  = pp / (OW / 2);
    int oy = t % OH;
    int b  = t / OH;

    const float* fb = f + (size_t)b * H * W;
    int iy0 = 4 * oy - 3;
    int ix0 = 4 * ox - 3;
    // second pixel's window starts at ix0+4, ends ix0+10.
    // max ix = 4*158-3+10 = 639, max iy = 4*119-3+6 = 479: right/bottom
    // never out of range; only left/top need zero-fill.

    float in[77];                        // 7 rows x 11 cols
    if (oy > 0 && ox > 0) {
        #pragma unroll
        for (int ky = 0; ky < 7; ky++) {
            const float* row = fb + (iy0 + ky) * W + ix0;
            #pragma unroll
            for (int kx = 0; kx < 11; kx++) in[ky * 11 + kx] = row[kx];
        }
    } else {
        #pragma unroll
        for (int ky = 0; ky < 7; ky++) {
            int iy = iy0 + ky;
            #pragma unroll
            for (int kx = 0; kx < 11; kx++) {
                int ix = ix0 + kx;
                in[ky * 11 + kx] = (iy >= 0 && ix >= 0) ? fb[iy * W + ix] : 0.0f;
            }
        }
    }

    const size_t plane = (size_t)(OH * OW);
    size_t obase = (size_t)b * CH * plane + (size_t)oy * OW + ox;
    #pragma unroll 1
    for (int c = c0; c < c0 + 16; c++) {
        const float* wfc = wf + c * 49;
        float bias = bf[c];
        float a0 = bias, a1 = bias;
        #pragma unroll
        for (int ky = 0; ky < 7; ky++) {
            #pragma unroll
            for (int kx = 0; kx < 7; kx++) {
                float wv = wfc[ky * 7 + kx];
                a0 = fmaf(wv, in[ky * 11 + kx],     a0);
                a1 = fmaf(wv, in[ky * 11 + kx + 4], a1);
            }
        }
        v2f r; r.x = fmaxf(a0, 0.0f); r.y = fmaxf(a1, 0.0f);
        // 8B-aligned (ox, OW even); nontemporal: don't pollute L2
        __builtin_nontemporal_store(
            r, (v2f*)(fmap + obase + (size_t)c * plane));
    }
}

// ---------------------------------------------------------------------------
// Kernel 2: fused Harris + per-cell argmax. One block per grid cell (30x40).
// !!! ACCUMULATION-ORDER-SENSITIVE: each pixel's 7x7 box sum MUST be the
// direct row-major (ky,kx) chain of individual adds. Separable / row-sum
// reassociation flips argmax ties (rounds 1 & 4: absmax 468). The register
// blocking below shares LDS READS only — every pixel still executes its own
// exact 49-add chain per array. !!!
// ---------------------------------------------------------------------------
__global__ __launch_bounds__(256) void harris_cell(
    const float* __restrict__ f, float* __restrict__ cval, int* __restrict__ cidx)
{
    __shared__ float sf[37][48];
    __shared__ float dxx[36][48], dyy[36][48], dxy[36][48];
    __shared__ float sv[256];
    __shared__ int   si[256];

    int cell = blockIdx.x;            // b*256 + gh*16 + gw
    int b  = cell >> 8;
    int ci = cell & 255;
    int gh = ci >> 4, gw = ci & 15;
    int cy0 = gh * PH, cx0 = gw * PW;
    const float* fb = f + (size_t)b * H * W;
    int tid = threadIdx.x;

    // load f rows [cy0-3, cy0+33] (37), cols [cx0-3, cx0+43] (47), clamped
    for (int i = tid; i < 37 * 47; i += 256) {
        int r = i / 47, c = i % 47;
        int y = min(max(cy0 - 3 + r, 0), H - 1);
        int x = min(max(cx0 - 3 + c, 0), W - 1);
        sf[r][c] = fb[(size_t)y * W + x];
    }
    __syncthreads();

    // derivative products at rows [cy0-3, cy0+32] (36), cols [cx0-3, cx0+42] (46)
    for (int i = tid; i < 36 * 46; i += 256) {
        int r = i / 46, c = i % 46;
        int y = cy0 - 3 + r;
        int x = cx0 - 3 + c;
        float vxx = 0.0f, vyy = 0.0f, vxy = 0.0f;
        if (y >= 0 && y < H && x >= 0 && x < W) {
            int xa = (x == W - 1) ? (x - 2) : x;    // dx[639] = dx[637]
            int ya = (y == H - 1) ? (y - 2) : y;    // dy[479] = dy[477]
            int lx = xa - (cx0 - 3);
            int ly = ya - (cy0 - 3);
            float dxv = sf[r][lx + 1] - sf[r][lx];
            float dyv = sf[ly + 1][c] - sf[ly][c];
            vxx = dxv * dxv;
            vyy = dyv * dyv;
            vxy = dxv * dyv;
        }
        dxx[r][c] = vxx; dyy[r][c] = vyy; dxy[r][c] = vxy;
    }
    __syncthreads();

    // Register-blocked box sums: thread = (col, 6-pixel vertical group).
    // Load each derivative row once (21 regs), add each value individually
    // to every covered pixel in exact (ky,kx) row-major order.
    float best = -INFINITY;
    int   bidx = 0x7fffffff;
    if (tid < 200) {
        int col = tid % 40;           // ix
        int grp = tid / 40;           // iy0 = grp*6, pixels iy0..iy0+5
        int iy0 = grp * 6;
        float axx[6] = {0,0,0,0,0,0};
        float ayy[6] = {0,0,0,0,0,0};
        float axy[6] = {0,0,0,0,0,0};
        #pragma unroll
        for (int r = 0; r < 12; r++) {
            float vxx[7], vyy[7], vxy[7];
            #pragma unroll
            for (int kx = 0; kx < 7; kx++) {
                vxx[kx] = dxx[iy0 + r][col + kx];
                vyy[kx] = dyy[iy0 + r][col + kx];
                vxy[kx] = dxy[iy0 + r][col + kx];
            }
            #pragma unroll
            for (int p = 0; p < 6; p++) {
                if (r - p >= 0 && r - p <= 6) {   // pixel p uses rows p..p+6
                    #pragma unroll
                    for (int kx = 0; kx < 7; kx++) {
                        axx[p] += vxx[kx];
                        ayy[p] += vyy[kx];
                        axy[p] += vxy[kx];
                    }
                }
            }
        }
        #pragma unroll
        for (int p = 0; p < 6; p++) {
            float Ixx = axx[p] / 49.0f;
            float Iyy = ayy[p] / 49.0f;
            float Ixy = axy[p] / 49.0f;
            float resp = (Ixx * Iyy - Ixy * Ixy) / (Ixx + Iyy + 1e-8f);
            int idx = (iy0 + p) * PW + col;
            if (resp > best) { best = resp; bidx = idx; }
        }
    }

    sv[tid] = best;
    si[tid] = bidx;
    __syncthreads();
    for (int s = 128; s > 0; s >>= 1) {
        if (tid < s) {
            float ov = sv[tid + s];
            int   oi = si[tid + s];
            if (ov > sv[tid] || (ov == sv[tid] && oi < si[tid])) {
                sv[tid] = ov; si[tid] = oi;
            }
        }
        __syncthreads();
    }
    if (tid == 0) { cval[cell] = sv[0]; cidx[cell] = si[0]; }
}

// ---------------------------------------------------------------------------
// Kernel 3: stable top-192 of 256 cell maxima per batch via O(256^2) ranking
// ---------------------------------------------------------------------------
__global__ __launch_bounds__(256) void topk_coords(
    const float* __restrict__ cval, const int* __restrict__ cidx,
    float* __restrict__ coords)
{
    int b = blockIdx.x;
    int j = threadIdx.x;
    __shared__ float v[256];
    v[j] = cval[b * 256 + j];
    __syncthreads();
    float vj = v[j];
    int rank = 0;
    for (int k = 0; k < 256; k++) {
        float vk = v[k];
        rank += (vk > vj) || (vk == vj && k < j);
    }
    if (rank < P) {
        int ii = cidx[b * 256 + j];
        int gh = j >> 4, gw = j & 15;
        int y = ii / PW + gh * PH;
        int x = ii % PW + gw * PW;
        coords[((size_t)b * P + rank) * 2 + 0] = (float)x;
        coords[((size_t)b * P + rank) * 2 + 1] = (float)y;
    }
}

// ---------------------------------------------------------------------------
// Kernel 4: patches. One block per (b,p) point. All 49 taps share one
// bilinear fraction; stage the 8x8x128 fmap window in LDS.
// patches_c: on-the-fly second conv at the 4 corner pixels.
// pf stores now NONTEMPORAL (38.5MB stream, never re-read: pure pollution).
// ---------------------------------------------------------------------------
__global__ __launch_bounds__(256) void patches_kern(
    const float* __restrict__ coords,
    const float* __restrict__ fmap,
    const float* __restrict__ frame,
    const float* __restrict__ wc, const float* __restrict__ bc,
    float* __restrict__ pf, float* __restrict__ pc)
{
    __shared__ float sfm[CH][64];      // 8 rows x 8 cols per channel, 32 KB
    __shared__ float sf2[14][16];
    __shared__ float vq[CH][5];

    int bp = blockIdx.x;               // 0 .. BN*P
    int b = bp / P;
    float cx = coords[(size_t)bp * 2 + 0] * 0.25f;   // /DS, exact
    float cy = coords[(size_t)bp * 2 + 1] * 0.25f;
    int tid = threadIdx.x;

    int X0 = (int)floorf(cx), Y0 = (int)floorf(cy);
    float wx = cx - (float)X0, wy = cy - (float)Y0;
    float w00 = (1.0f - wx) * (1.0f - wy);
    float w10 = wx * (1.0f - wy);
    float w01 = (1.0f - wx) * wy;
    float w11 = wx * wy;

    // stage fmap window rows [Y0-3, Y0+4], cols [X0-3, X0+4], all channels
    const float* fm = fmap + (size_t)b * CH * (OH * OW);
    for (int i = tid; i < CH * 64; i += 256) {
        int ch = i >> 6;
        int off = i & 63;
        int r = off >> 3, c = off & 7;
        int gy = Y0 - 3 + r, gx = X0 - 3 + c;
        sfm[ch][off] = (gy >= 0 && gy < OH && gx >= 0 && gx < OW)
                     ? fm[(size_t)ch * (OH * OW) + gy * OW + gx] : 0.0f;
    }

    // stage 14x14 input patch for the on-the-fly conv (zero outside image)
    int ix0 = 4 * X0 - 3, iy0 = 4 * Y0 - 3;
    const float* frb = frame + (size_t)b * H * W;
    for (int i = tid; i < 14 * 14; i += 256) {
        int r = i / 14, c = i % 14;
        int y = iy0 + r, x = ix0 + c;
        sf2[r][c] = (y >= 0 && y < H && x >= 0 && x < W)
                  ? frb[(size_t)y * W + x] : 0.0f;
    }
    __syncthreads();

    // ---- patches_f: bilinear from LDS ----
    size_t pfbase = (size_t)bp * CH * 49;
    for (int idx = tid; idx < CH * 49; idx += 256) {
        int c = idx / 49;
        int k = idx - c * 49;
        int ky = k / 7, kx = k - ky * 7;
        int o = ky * 8 + kx;
        float acc = w00 * sfm[c][o]
                  + w10 * sfm[c][o + 1]
                  + w01 * sfm[c][o + 8]
                  + w11 * sfm[c][o + 9];
        __builtin_nontemporal_store(acc, &pf[pfbase + idx]);
    }

    // ---- on-the-fly second conv at the 4 corner pixels ----
    for (int idx = tid; idx < 512; idx += 256) {
        int q = idx & 3;            // (qx,qy) = (q&1, q>>1)
        int c = idx >> 2;
        int qx = q & 1, qy = q >> 1;
        const float* wcc = wc + c * 49;
        float acc = bc[c];
        #pragma unroll
        for (int ky = 0; ky < 7; ky++) {
            #pragma unroll
            for (int kx = 0; kx < 7; kx++)
                acc = fmaf(wcc[ky * 7 + kx], sf2[4 * qy + ky][4 * qx + kx], acc);
        }
        vq[c][q] = fmaxf(acc, 0.0f);
    }
    __syncthreads();

    // ---- patches_c: bilinear combine with boundary masks ----
    float m00 = (X0 >= 0 && X0 < OW && Y0 >= 0 && Y0 < OH) ? 1.0f : 0.0f;
    float m10 = (X0 + 1 >= 0 && X0 + 1 < OW && Y0 >= 0 && Y0 < OH) ? 1.0f : 0.0f;
    float m01 = (X0 >= 0 && X0 < OW && Y0 + 1 >= 0 && Y0 + 1 < OH) ? 1.0f : 0.0f;
    float m11 = (X0 + 1 >= 0 && X0 + 1 < OW && Y0 + 1 >= 0 && Y0 + 1 < OH) ? 1.0f : 0.0f;
    if (tid < CH) {
        float acc = w00 * m00 * vq[tid][0] + w10 * m10 * vq[tid][1]
                  + w01 * m01 * vq[tid][2] + w11 * m11 * vq[tid][3];
        pc[(size_t)bp * CH + tid] = acc;
    }
}

// ---------------------------------------------------------------------------
// Launch
// ---------------------------------------------------------------------------
extern "C" void kernel_launch(void* const* d_in, const int* in_sizes, int n_in,
                              void* d_out, int out_size, void* d_ws, size_t ws_size,
                              hipStream_t stream)
{
    const float* frame = (const float*)d_in[0];
    const float* w_f   = (const float*)d_in[1];
    const float* b_f   = (const float*)d_in[2];
    const float* w_c   = (const float*)d_in[3];
    const float* b_c   = (const float*)d_in[4];

    float* out = (float*)d_out;
    // output layout: coords | patches_f | patches_c | fmap
    const size_t coords_sz = (size_t)BN * P * 2;                 // 3072
    const size_t pf_sz     = (size_t)BN * P * CH * 49;           // 9,633,792
    const size_t pc_sz     = (size_t)BN * P * CH;                // 196,608
    float* coords = out;
    float* pf     = out + coords_sz;
    float* pc     = out + coords_sz + pf_sz;
    float* fmap   = out + coords_sz + pf_sz + pc_sz;

    // workspace: only cell argmax state (16 KB)
    float* cval = (float*)d_ws;                                  // 2048 f
    int*   cidx = (int*)(cval + BN * 256);                       // 2048 i

    // 76800 pixel-pairs / 256 = 300 blocks x 8 channel groups (16 ch/thread)
    dim3 cg((BN * OH * (OW / 2)) / 256, 8);
    conv_enc<<<cg, 256, 0, stream>>>(frame, w_f, b_f, fmap);

    harris_cell<<<BN * 256, 256, 0, stream>>>(frame, cval, cidx);

    topk_coords<<<BN, 256, 0, stream>>>(cval, cidx, coords);

    patches_kern<<<BN * P, 256, 0, stream>>>(
        coords, fmap, frame, w_c, b_c, pf, pc);
}